// Round 1
// baseline (547.525 us; speedup 1.0000x reference)
//
#include <hip/hip_runtime.h>
#include <hip/hip_bf16.h>

typedef __attribute__((ext_vector_type(8))) short short8;
typedef __attribute__((ext_vector_type(4))) float f32x4;

static constexpr int T_TOTAL = 500;
static constexpr int BATCH   = 256;
static constexpr int NIN     = 128;
static constexpr int NH1     = 512;
static constexpr int NH2     = 256;
static constexpr int TC      = 100;   // chunk length
static constexpr int NCHUNK  = 5;

__device__ __forceinline__ unsigned short f2bf(float x) {
    __hip_bfloat16 h = __float2bfloat16(x);
    return *reinterpret_cast<unsigned short*>(&h);
}
__device__ __forceinline__ float bf2f(unsigned short u) {
    __hip_bfloat16 h;
    *reinterpret_cast<unsigned short*>(&h) = u;
    return __bfloat162float(h);
}

// Split f32 weights into 3 exact bf16 components: w ≈ hi + mid + lo (≈24 bits)
__global__ __launch_bounds__(256) void prep_weights(
    const float* __restrict__ W1, const float* __restrict__ W2,
    unsigned short* __restrict__ w1s,   // [3][512*128]
    unsigned short* __restrict__ w2s)   // [3][256*512]
{
    int idx = blockIdx.x * 256 + threadIdx.x;
    const int n1 = NH1 * NIN;   // 65536
    const int n2 = NH2 * NH1;   // 131072
    if (idx < n1) {
        float w = W1[idx];
        unsigned short hi = f2bf(w);  float r = w - bf2f(hi);
        unsigned short mi = f2bf(r);  r -= bf2f(mi);
        unsigned short lo = f2bf(r);
        w1s[idx] = hi; w1s[n1 + idx] = mi; w1s[2*n1 + idx] = lo;
    }
    if (idx < n2) {
        float w = W2[idx];
        unsigned short hi = f2bf(w);  float r = w - bf2f(hi);
        unsigned short mi = f2bf(r);  r -= bf2f(mi);
        unsigned short lo = f2bf(r);
        w2s[idx] = hi; w2s[n2 + idx] = mi; w2s[2*n2 + idx] = lo;
    }
}

// spikes f32 (exact 0/1) -> bf16
__global__ __launch_bounds__(256) void prep_spikes(
    const float* __restrict__ sp, unsigned short* __restrict__ spb)
{
    int i = blockIdx.x * 256 + threadIdx.x;     // 4,096,000 threads
    int idx4 = i * 4;
    float4 v = *reinterpret_cast<const float4*>(sp + idx4);
    ushort4 o;
    o.x = f2bf(v.x); o.y = f2bf(v.y); o.z = f2bf(v.z); o.w = f2bf(v.w);
    *reinterpret_cast<ushort4*>(spb + idx4) = o;
}

// C[M,N] = A[M,K](bf16) * (B_hi+B_mid+B_lo)[N,K](bf16, row-major = B^T) + bias
// BM=128 BN=64 BK=32, 256 threads (4 waves), wave w owns rows [32w,32w+32)
__global__ __launch_bounds__(256) void gemm_splits(
    const unsigned short* __restrict__ A,
    const unsigned short* __restrict__ Bs,   // [3][N*K]
    const float* __restrict__ bias,
    float* __restrict__ C,
    int M, int N, int K)
{
    constexpr int BM = 128, BN = 64, BK = 32;
    constexpr int LP = 40;                      // padded row stride (ushorts)
    __shared__ unsigned short As[BM * LP];      // 10240 B
    __shared__ unsigned short Bsh[3 * BN * LP]; // 15360 B

    const int tid  = threadIdx.x;
    const int w    = tid >> 6;
    const int lane = tid & 63;
    const int lr   = lane & 15;
    const int lk   = lane >> 4;

    const int m0 = blockIdx.x * BM;
    const int n0 = blockIdx.y * BN;
    const size_t NK = (size_t)N * K;

    f32x4 acc[2][4];
#pragma unroll
    for (int i = 0; i < 2; ++i)
#pragma unroll
        for (int j = 0; j < 4; ++j) acc[i][j] = (f32x4){0.f, 0.f, 0.f, 0.f};

    const int nk = K / BK;
    for (int ks = 0; ks < nk; ++ks) {
        const int k0 = ks * BK;
        // stage A tile: 128x32 bf16 = 512 16B-units, 2 per thread
#pragma unroll
        for (int u0 = 0; u0 < 2; ++u0) {
            int u = tid + u0 * 256;
            int row = u >> 2, c8 = u & 3;
            const unsigned short* gp = A + (size_t)(m0 + row) * K + k0 + c8 * 8;
            int4 v = *reinterpret_cast<const int4*>(gp);
            *reinterpret_cast<int4*>(&As[row * LP + c8 * 8]) = v;
        }
        // stage B tiles: 3 x 64x32 bf16 = 768 units, 3 per thread
#pragma unroll
        for (int u0 = 0; u0 < 3; ++u0) {
            int u = tid + u0 * 256;
            int s = u >> 8;
            int r = u & 255;
            int row = r >> 2, c8 = r & 3;
            const unsigned short* gp = Bs + (size_t)s * NK + (size_t)(n0 + row) * K + k0 + c8 * 8;
            int4 v = *reinterpret_cast<const int4*>(gp);
            *reinterpret_cast<int4*>(&Bsh[s * (BN * LP) + row * LP + c8 * 8]) = v;
        }
        __syncthreads();

        short8 af[2];
#pragma unroll
        for (int rb = 0; rb < 2; ++rb)
            af[rb] = *reinterpret_cast<const short8*>(&As[(w * 32 + rb * 16 + lr) * LP + lk * 8]);
#pragma unroll
        for (int s = 0; s < 3; ++s) {
#pragma unroll
            for (int cb = 0; cb < 4; ++cb) {
                short8 bf = *reinterpret_cast<const short8*>(
                    &Bsh[s * (BN * LP) + (cb * 16 + lr) * LP + lk * 8]);
#pragma unroll
                for (int rb = 0; rb < 2; ++rb)
                    acc[rb][cb] = __builtin_amdgcn_mfma_f32_16x16x32_bf16(
                        af[rb], bf, acc[rb][cb], 0, 0, 0);
            }
        }
        __syncthreads();
    }

    // epilogue: C/D layout col=lane&15, row=(lane>>4)*4+j
#pragma unroll
    for (int cb = 0; cb < 4; ++cb) {
        int col = n0 + cb * 16 + lr;
        float bv = bias[col];
#pragma unroll
        for (int rb = 0; rb < 2; ++rb) {
            int row = m0 + w * 32 + rb * 16 + lk * 4;
#pragma unroll
            for (int j = 0; j < 4; ++j)
                C[(size_t)(row + j) * N + col] = acc[rb][cb][j] + bv;
        }
    }
}

// LIF scan layer 1: mem = b*mem + cur - s_prev; s = (mem>1); emit spk bf16
__global__ __launch_bounds__(256) void scan1(
    const float* __restrict__ cur,            // [TC*131072]
    unsigned short* __restrict__ spk,         // [TC*131072] bf16
    float* __restrict__ mem_c, float* __restrict__ s_c, float* __restrict__ sum_c,
    int first)
{
    int tid = blockIdx.x * 256 + threadIdx.x;  // 131072
    float mem = first ? 0.f : mem_c[tid];
    float s   = first ? 0.f : s_c[tid];
    float sum = first ? 0.f : sum_c[tid];
    const float beta = 0.8187307530779818f;    // exp(-1/5)
    for (int t = 0; t < TC; ++t) {
        size_t off = (size_t)t * 131072 + tid;
        float c = cur[off];
        mem = beta * mem + c - s;
        s = (mem > 1.f) ? 1.f : 0.f;
        sum += s;
        spk[off] = (s > 0.5f) ? (unsigned short)0x3F80 : (unsigned short)0;
    }
    mem_c[tid] = mem; s_c[tid] = s; sum_c[tid] = sum;
}

// LIF scan layer 2: also accumulate mem-sum and spike count
__global__ __launch_bounds__(256) void scan2(
    const float* __restrict__ cur,             // [TC*65536]
    float* __restrict__ mem_c, float* __restrict__ s_c,
    float* __restrict__ msum_c, float* __restrict__ cnt_c,
    int first)
{
    int tid = blockIdx.x * 256 + threadIdx.x;  // 65536
    float mem  = first ? 0.f : mem_c[tid];
    float s    = first ? 0.f : s_c[tid];
    float msum = first ? 0.f : msum_c[tid];
    float cnt  = first ? 0.f : cnt_c[tid];
    const float beta = 0.9048374180359595f;    // exp(-1/10)
    for (int t = 0; t < TC; ++t) {
        float c = cur[(size_t)t * 65536 + tid];
        mem = beta * mem + c - s;
        s = (mem > 1.f) ? 1.f : 0.f;
        msum += mem;
        cnt += s;
    }
    mem_c[tid] = mem; s_c[tid] = s; msum_c[tid] = msum; cnt_c[tid] = cnt;
}

// out[b,o] = (msum[b,:]/T)@Wr[o,:] + br[o] + (s1sum[b,:]/T)@Ws[o,:] + bs[o]
__global__ __launch_bounds__(256) void readout(
    const float* __restrict__ msum, const float* __restrict__ s1sum,
    const float* __restrict__ Wr, const float* __restrict__ br,
    const float* __restrict__ Ws, const float* __restrict__ bs,
    float* __restrict__ out)
{
    __shared__ float r0[256], r1[256];
    int b = blockIdx.x, t = threadIdx.x;
    const float inv_t = 1.0f / 500.0f;
    float m  = msum[b * 256 + t] * inv_t;
    float p0 = m * Wr[t];
    float p1 = m * Wr[256 + t];
    float sa = s1sum[b * 512 + t] * inv_t;
    float sb = s1sum[b * 512 + 256 + t] * inv_t;
    p0 += sa * Ws[t]       + sb * Ws[256 + t];
    p1 += sa * Ws[512 + t] + sb * Ws[768 + t];
    r0[t] = p0; r1[t] = p1;
    __syncthreads();
    for (int st = 128; st > 0; st >>= 1) {
        if (t < st) { r0[t] += r0[t + st]; r1[t] += r1[t + st]; }
        __syncthreads();
    }
    if (t == 0) {
        out[b * 2 + 0] = r0[0] + br[0] + bs[0];
        out[b * 2 + 1] = r1[0] + br[1] + bs[1];
    }
}

__global__ __launch_bounds__(256) void scalars(
    const float* __restrict__ s1sum, const float* __restrict__ s2cnt,
    float* __restrict__ out)
{
    __shared__ float r[256];
    int t = threadIdx.x;
    float a = 0.f;
    for (int i = t; i < 131072; i += 256) a += s1sum[i];
    r[t] = a; __syncthreads();
    for (int st = 128; st > 0; st >>= 1) {
        if (t < st) r[t] += r[t + st];
        __syncthreads();
    }
    if (t == 0) out[512] = r[0] * (1.0f / 65536000.0f);
    __syncthreads();
    float c = 0.f;
    for (int i = t; i < 65536; i += 256) c += s2cnt[i];
    r[t] = c; __syncthreads();
    for (int st = 128; st > 0; st >>= 1) {
        if (t < st) r[t] += r[t + st];
        __syncthreads();
    }
    if (t == 0) out[513] = r[0] * (1.0f / 32768000.0f);
}

extern "C" void kernel_launch(void* const* d_in, const int* in_sizes, int n_in,
                              void* d_out, int out_size, void* d_ws, size_t ws_size,
                              hipStream_t stream) {
    const float* spikes = (const float*)d_in[0];
    const float* W1 = (const float*)d_in[1];
    const float* b1 = (const float*)d_in[2];
    const float* W2 = (const float*)d_in[3];
    const float* b2 = (const float*)d_in[4];
    const float* Wr = (const float*)d_in[5];
    const float* br = (const float*)d_in[6];
    const float* Ws = (const float*)d_in[7];
    const float* bs = (const float*)d_in[8];
    float* out = (float*)d_out;

    char* wsb = (char*)d_ws;
    size_t o = 0;
    unsigned short* w1s  = (unsigned short*)(wsb + o); o += (size_t)3 * 65536 * 2;      // 393216
    unsigned short* w2s  = (unsigned short*)(wsb + o); o += (size_t)3 * 131072 * 2;     // 786432
    unsigned short* sp16 = (unsigned short*)(wsb + o); o += (size_t)16384000 * 2;       // 32.77MB
    float*          cur1 = (float*)(wsb + o);          o += (size_t)TC * 131072 * 4;    // 52.4MB
    unsigned short* spk1 = (unsigned short*)(wsb + o); o += (size_t)TC * 131072 * 2;    // 26.2MB
    float*          cur2 = (float*)(wsb + o);          o += (size_t)TC * 65536 * 4;     // 26.2MB
    float* mem1  = (float*)(wsb + o); o += 524288;
    float* s1    = (float*)(wsb + o); o += 524288;
    float* s1sum = (float*)(wsb + o); o += 524288;
    float* mem2  = (float*)(wsb + o); o += 262144;
    float* s2    = (float*)(wsb + o); o += 262144;
    float* msum  = (float*)(wsb + o); o += 262144;
    float* cnt   = (float*)(wsb + o); o += 262144;

    prep_weights<<<512, 256, 0, stream>>>(W1, W2, w1s, w2s);
    prep_spikes<<<16000, 256, 0, stream>>>(spikes, sp16);

    const int MC = TC * BATCH;   // 25600 rows per chunk
    for (int c = 0; c < NCHUNK; ++c) {
        const unsigned short* Ac = sp16 + (size_t)c * MC * NIN;
        gemm_splits<<<dim3(MC / 128, NH1 / 64), 256, 0, stream>>>(
            Ac, w1s, b1, cur1, MC, NH1, NIN);
        scan1<<<512, 256, 0, stream>>>(cur1, spk1, mem1, s1, s1sum, c == 0);
        gemm_splits<<<dim3(MC / 128, NH2 / 64), 256, 0, stream>>>(
            spk1, w2s, b2, cur2, MC, NH2, NH1);
        scan2<<<256, 256, 0, stream>>>(cur2, mem2, s2, msum, cnt, c == 0);
    }

    readout<<<256, 256, 0, stream>>>(msum, s1sum, Wr, br, Ws, bs, out);
    scalars<<<1, 256, 0, stream>>>(s1sum, cnt, out);
}